// Round 9
// baseline (449.904 us; speedup 1.0000x reference)
//
#include <hip/hip_runtime.h>

#define T_ 30
#define H_ 41
#define WD_ 2048
#define NSEC 9
#define FM 50
#define WP 502
#define THRESH 23.0f
#define POOLED_SIZE (NSEC * T_ * FM * WP)   // 6,777,000
#define MARGIN 0.0078125f                   // 2^-7 >= worst-case split error
#define NFRAG 18432                         // 9 sec * 64 fm * 32 tap-octets

typedef short short8 __attribute__((ext_vector_type(8)));
typedef short short4v __attribute__((ext_vector_type(4)));
typedef float f32x4 __attribute__((ext_vector_type(4)));

__device__ __forceinline__ unsigned bf16_rne(float f) {
    unsigned u = __float_as_uint(f);
    return (u + 0x7fffu + ((u >> 16) & 1u)) >> 16;
}

// ---------------- prep: W -> MFMA-ready bf16 hi/lo fragments in ws --------
__global__ __launch_bounds__(256) void prep_kernel(
    const float* __restrict__ Wg, int* __restrict__ wsi,
    uint4* __restrict__ wfh, uint4* __restrict__ wfl)
{
    const int gid = blockIdx.x * 256 + threadIdx.x;
    if (gid < NSEC) wsi[gid] = 0x7fffffff;
    if (gid >= NFRAG) return;
    const int blk = gid & 31;
    const int fm  = (gid >> 5) & 63;
    const int sec = gid >> 11;
    const int t0  = blk * 8;
    const bool valid = (t0 < 240) && (fm < FM);
    unsigned hh[4], ll[4];
    const float* wp = Wg + ((size_t)sec * FM + (valid ? fm : 0)) * 240 + (valid ? t0 : 0);
    float4 wa = *reinterpret_cast<const float4*>(wp);
    float4 wb = *reinterpret_cast<const float4*>(wp + 4);
    float f[8] = {wa.x, wa.y, wa.z, wa.w, wb.x, wb.y, wb.z, wb.w};
#pragma unroll
    for (int i = 0; i < 4; ++i) {
        float f0 = valid ? f[2 * i] : 0.f;
        float f1 = valid ? f[2 * i + 1] : 0.f;
        unsigned h0 = bf16_rne(f0), h1 = bf16_rne(f1);
        float hf0 = __uint_as_float(h0 << 16), hf1 = __uint_as_float(h1 << 16);
        unsigned l0 = bf16_rne(f0 - hf0), l1 = bf16_rne(f1 - hf1);
        hh[i] = (h1 << 16) | h0;
        ll[i] = (l1 << 16) | l0;
    }
    wfh[gid] = *reinterpret_cast<uint4*>(hh);
    wfl[gid] = *reinterpret_cast<uint4*>(ll);
}

// fallback in-kernel W frag build (non-PRE path only)
__device__ __forceinline__ void build_wfrag(
    const float* __restrict__ Wg, int sec, int fm, int t0,
    short8* wh, short8* wl)
{
    const bool wvalid = (t0 < 240) && (fm < FM);
    const float* wp = Wg + (size_t)sec * FM * 240 +
                      (size_t)(wvalid ? fm : 0) * 240 + (wvalid ? t0 : 0);
    float4 wa = *reinterpret_cast<const float4*>(wp);
    float4 wb = *reinterpret_cast<const float4*>(wp + 4);
    float f[8] = {wa.x, wa.y, wa.z, wa.w, wb.x, wb.y, wb.z, wb.w};
    unsigned hh[4], ll[4];
#pragma unroll
    for (int i = 0; i < 4; ++i) {
        float f0 = wvalid ? f[2 * i] : 0.f;
        float f1 = wvalid ? f[2 * i + 1] : 0.f;
        unsigned h0 = bf16_rne(f0), h1 = bf16_rne(f1);
        float hf0 = __uint_as_float(h0 << 16), hf1 = __uint_as_float(h1 << 16);
        unsigned l0 = bf16_rne(f0 - hf0), l1 = bf16_rne(f1 - hf1);
        hh[i] = (h1 << 16) | h0;
        ll[i] = (l1 << 16) | l0;
    }
    *wh = *reinterpret_cast<short8*>(hh);
    *wl = *reinterpret_cast<short8*>(ll);
}

// ---------------- Kernel A: split-bf16 MFMA conv + fire + pool + argmin ----
// R8 geometry (verified). R9: (a) ft-PAIR weight residency — each ah/al LDS
// read feeds 6 MFMAs (two fm-tiles) instead of 3, halving LDS traffic (the
// R8 bound, ~173 us/CU). Weight frags (128 regs) park in AGPRs per R8's
// VGPR_Count=60 observation. (b) first-spike argmin fused: block reduces
// min-e over its lmask bits and does ONE atomicMin per block — scan_kernel
// (43 us of pooled re-read) deleted. res loop stays `#pragma unroll 1` (R7!).
template <bool PRE>
__global__ __launch_bounds__(256) void conv_pool_kernel(
    const float* __restrict__ x, const float* __restrict__ Wg,
    const uint4* __restrict__ wfh, const uint4* __restrict__ wfl,
    float* __restrict__ out, int* __restrict__ keys)
{
    __shared__ __align__(16) unsigned short xh[4][10][176];   // 13.75 KB
    __shared__ __align__(16) unsigned short xl[4][10][176];   // 13.75 KB
    __shared__ unsigned lmask[4][64];
    __shared__ int red[256];

    const int b       = blockIdx.x;
    const int coltile = b & 15;
    const int tt      = (b >> 4) % T_;
    const int sec     = b / 480;
    const int w0      = coltile * 128;     // pot-col base
    const int rowbase = 4 * sec;
    const int tid     = threadIdx.x;

    // ---- stage x: 10 rows x 176 cols -> hi/lo u16, 4 shifted copies ----
    for (int i = tid; i < 440; i += 256) {
        const int row = i / 44;
        const int c4  = i % 44;
        const int grow = (rowbase + row < H_) ? rowbase + row : H_ - 1;
        const int gc   = w0 + 4 * c4;
        float4 v;
        if (gc + 3 < WD_) {
            v = *reinterpret_cast<const float4*>(x + ((size_t)tt * H_ + grow) * WD_ + gc);
        } else {
            v.x = v.y = v.z = v.w = 0.f;
        }
        float f[4] = {v.x, v.y, v.z, v.w};
        unsigned short hq[4], lq[4];
#pragma unroll
        for (int e = 0; e < 4; ++e) {
            unsigned h = bf16_rne(f[e]);
            float hf = __uint_as_float(h << 16);
            unsigned l = bf16_rne(f[e] - hf);
            hq[e] = (unsigned short)h;
            lq[e] = (unsigned short)l;
        }
#pragma unroll
        for (int S = 0; S < 4; ++S)
#pragma unroll
            for (int e = 0; e < 4; ++e) {
                const int j = 4 * c4 + e - S;
                if (j >= 0 && j < 176) { xh[S][row][j] = hq[e]; xl[S][row][j] = lq[e]; }
            }
    }
    __syncthreads();

    const int L    = tid & 63;
    const int j_p  = tid >> 6;       // wave id = pot row
    const int q    = L >> 4;         // quad
    const int n16  = L & 15;         // A: m-index; B: fm-index

    // per-kk tap geometry (tau0 = 32kk + 8q -> weight row r, col c0)
    int preidx[8];
    int tau0s[8];
#pragma unroll
    for (int kk = 0; kk < 8; ++kk) {
        const int t0 = 32 * kk + 8 * q;
        const int r  = t0 / 40;
        const int c0 = t0 - 40 * r;
        tau0s[kk]  = t0;
        preidx[kk] = (j_p + r) * 176 + c0 + 8 * n16;
    }

    unsigned mask = 0;

#pragma unroll 1
    for (int fp = 0; fp < 2; ++fp) {          // ft-PAIR: tiles 2fp, 2fp+1
        const int ft0 = 2 * fp, ft1 = 2 * fp + 1;
        const int fmA = ft0 * 16 + n16;
        const int fmB = ft1 * 16 + n16;
        short8 wh0[8], wl0[8], wh1[8], wl1[8];
        if (PRE) {
            const int fb0 = (sec * 64 + ft0 * 16 + n16) * 32 + q;
            const int fb1 = (sec * 64 + ft1 * 16 + n16) * 32 + q;
#pragma unroll
            for (int kk = 0; kk < 8; ++kk) {
                union { uint4 u; short8 s; } c;
                c.u = wfh[fb0 + 4 * kk]; wh0[kk] = c.s;
                c.u = wfl[fb0 + 4 * kk]; wl0[kk] = c.s;
                c.u = wfh[fb1 + 4 * kk]; wh1[kk] = c.s;
                c.u = wfl[fb1 + 4 * kk]; wl1[kk] = c.s;
            }
        } else {
#pragma unroll
            for (int kk = 0; kk < 8; ++kk) {
                build_wfrag(Wg, sec, fmA, tau0s[kk], &wh0[kk], &wl0[kk]);
                build_wfrag(Wg, sec, fmB, tau0s[kk], &wh1[kk], &wl1[kk]);
            }
        }

#pragma unroll 1
        for (int res = 0; res < 8; ++res) {
            const int S   = res & 3;
            const int off = (res >> 2) << 2;          // 0 or 4 cols
            const unsigned short* hb = &xh[S][0][0] + off;
            const unsigned short* lb = &xl[S][0][0] + off;

            f32x4 acc0 = {0.f, 0.f, 0.f, 0.f};
            f32x4 acc1 = {0.f, 0.f, 0.f, 0.f};
#pragma unroll
            for (int kk = 0; kk < 8; ++kk) {
                short8 ah, al;
                if (off == 0) {                       // 16B-aligned: b128
                    ah = *reinterpret_cast<const short8*>(hb + preidx[kk]);
                    al = *reinterpret_cast<const short8*>(lb + preidx[kk]);
                } else {                              // 8B-aligned: 2x b64
                    short4v h0 = *reinterpret_cast<const short4v*>(hb + preidx[kk]);
                    short4v h1 = *reinterpret_cast<const short4v*>(hb + preidx[kk] + 4);
                    short4v l0 = *reinterpret_cast<const short4v*>(lb + preidx[kk]);
                    short4v l1 = *reinterpret_cast<const short4v*>(lb + preidx[kk] + 4);
                    ah = __builtin_shufflevector(h0, h1, 0, 1, 2, 3, 4, 5, 6, 7);
                    al = __builtin_shufflevector(l0, l1, 0, 1, 2, 3, 4, 5, 6, 7);
                }
                acc0 = __builtin_amdgcn_mfma_f32_16x16x32_bf16(ah, wh0[kk], acc0, 0, 0, 0);
                acc1 = __builtin_amdgcn_mfma_f32_16x16x32_bf16(ah, wh1[kk], acc1, 0, 0, 0);
                acc0 = __builtin_amdgcn_mfma_f32_16x16x32_bf16(al, wh0[kk], acc0, 0, 0, 0);
                acc1 = __builtin_amdgcn_mfma_f32_16x16x32_bf16(al, wh1[kk], acc1, 0, 0, 0);
                acc0 = __builtin_amdgcn_mfma_f32_16x16x32_bf16(ah, wl0[kk], acc0, 0, 0, 0);
                acc1 = __builtin_amdgcn_mfma_f32_16x16x32_bf16(ah, wl1[kk], acc1, 0, 0, 0);
            }

            // ---- epilogue: repair borderline, set pool bits (both tiles) ----
#pragma unroll
            for (int half = 0; half < 2; ++half) {
                const f32x4 acc = half ? acc1 : acc0;
                const int ft = half ? ft1 : ft0;
                const int fm = half ? fmB : fmA;
#pragma unroll
                for (int reg = 0; reg < 4; ++reg) {
                    float v = acc[reg];
                    const int m   = q * 4 + reg;
                    const int pcg = w0 + res + 8 * m;     // global pot col
                    const bool valid = (fm < FM) && (pcg <= 2007);
                    if (valid && __builtin_fabsf(v - THRESH) < MARGIN) {
                        float pot = 0.f;
#pragma unroll 1
                        for (int r2 = 0; r2 < 6; ++r2) {
                            const float* xr = x + ((size_t)tt * H_ + rowbase + j_p + r2) * WD_ + pcg;
                            const float* wr = Wg + (size_t)sec * FM * 240 + (size_t)fm * 240 + r2 * 40;
#pragma unroll 1
                            for (int c = 0; c < 40; ++c)
                                pot = fmaf(xr[c], wr[c], pot);
                        }
                        v = pot;
                    }
                    if (v > THRESH)
                        mask |= 1u << (reg * 8 + ft * 2 + (res >> 2));
                }
            }
        }
    }

    lmask[j_p][L] = mask;
    __syncthreads();

    // ---- cross-wave OR + pooled write + per-thread min-e candidate ----
    int mykey = 0x7fffffff;
    for (int e = tid; e < 2048; e += 256) {
        const int fmo = e >> 5, p = e & 31;
        const int m = p >> 1, rg = p & 1, ftc = fmo >> 4, fn = fmo & 15;
        const int lane = (m >> 2) * 16 + fn;
        const int bitpos = (m & 3) * 8 + ftc * 2 + rg;
        const unsigned bits = lmask[0][lane] | lmask[1][lane] |
                              lmask[2][lane] | lmask[3][lane];
        const int pg = coltile * 32 + p;
        const int spk = (bits >> bitpos) & 1u;
        if (fmo < FM && pg < WP) {
            out[((size_t)(sec * T_ + tt) * FM + fmo) * WP + pg] = spk ? 1.0f : 0.0f;
            if (spk) {
                const int gidx = fmo * WP + pg;          // section-flat index
                mykey = min(mykey, gidx);                // e ascending per thread
            }
        }
    }
    red[tid] = mykey;
    __syncthreads();
    for (int s = 128; s > 0; s >>= 1) {
        if (tid < s) red[tid] = min(red[tid], red[tid + s]);
        __syncthreads();
    }
    if (tid == 0 && red[0] != 0x7fffffff)
        atomicMin(&keys[sec], (tt << 15) | red[0]);
}

// ---------------- init (fallback only) ----------------
__global__ void init_kernel(int* __restrict__ ws)
{
    if (threadIdx.x < NSEC) ws[threadIdx.x] = 0x7fffffff;
}

// ---------------- Kernel D: finalize winners ----------------
__global__ void finalize_kernel(const int* __restrict__ ws, float* __restrict__ out)
{
    const int i = threadIdx.x;
    if (i < NSEC) {
        const int key = ws[i];
        float feat;
        if (key == 0x7fffffff) feat = -1.0f;
        else                   feat = (float)((key & 32767) / WP);
        out[POOLED_SIZE + i] = feat;
    }
}

extern "C" void kernel_launch(void* const* d_in, const int* in_sizes, int n_in,
                              void* d_out, int out_size, void* d_ws, size_t ws_size,
                              hipStream_t stream) {
    const float* x  = (const float*)d_in[0];
    const float* Wg = (const float*)d_in[1];
    float* out = (float*)d_out;
    int*   wsi = (int*)d_ws;
    uint4* wfh = (uint4*)((char*)d_ws + 256);
    uint4* wfl = wfh + NFRAG;

    const bool pre = ws_size >= 256 + (size_t)NFRAG * 16 * 2;   // 590 KB
    if (pre) {
        prep_kernel<<<dim3(72), dim3(256), 0, stream>>>(Wg, wsi, wfh, wfl);
        conv_pool_kernel<true><<<dim3(4320), dim3(256), 0, stream>>>(x, Wg, wfh, wfl, out, wsi);
    } else {
        init_kernel<<<dim3(1), dim3(64), 0, stream>>>(wsi);
        conv_pool_kernel<false><<<dim3(4320), dim3(256), 0, stream>>>(x, Wg, wfh, wfl, out, wsi);
    }
    finalize_kernel<<<dim3(1), dim3(16), 0, stream>>>(wsi, out);
}

// Round 10
// 356.425 us; speedup vs baseline: 1.2623x; 1.2623x over previous
//
#include <hip/hip_runtime.h>

#define T_ 30
#define H_ 41
#define WD_ 2048
#define NSEC 9
#define FM 50
#define WP 502
#define THRESH 23.0f
#define POOLED_SIZE (NSEC * T_ * FM * WP)   // 6,777,000
#define MARGIN 0.0078125f                   // 2^-7 >= worst-case split error
#define NFRAG 18432                         // 9 sec * 64 fm * 32 tap-octets

typedef short short8 __attribute__((ext_vector_type(8)));
typedef short short4v __attribute__((ext_vector_type(4)));
typedef float f32x4 __attribute__((ext_vector_type(4)));

__device__ __forceinline__ unsigned bf16_rne(float f) {
    unsigned u = __float_as_uint(f);
    return (u + 0x7fffu + ((u >> 16) & 1u)) >> 16;
}

// ---------------- prep: W -> MFMA-ready bf16 hi/lo fragments in ws --------
__global__ __launch_bounds__(256) void prep_kernel(
    const float* __restrict__ Wg, int* __restrict__ wsi,
    uint4* __restrict__ wfh, uint4* __restrict__ wfl)
{
    const int gid = blockIdx.x * 256 + threadIdx.x;
    if (gid < NSEC) wsi[gid] = 0x7fffffff;
    if (gid >= NFRAG) return;
    const int blk = gid & 31;
    const int fm  = (gid >> 5) & 63;
    const int sec = gid >> 11;
    const int t0  = blk * 8;
    const bool valid = (t0 < 240) && (fm < FM);
    unsigned hh[4], ll[4];
    const float* wp = Wg + ((size_t)sec * FM + (valid ? fm : 0)) * 240 + (valid ? t0 : 0);
    float4 wa = *reinterpret_cast<const float4*>(wp);
    float4 wb = *reinterpret_cast<const float4*>(wp + 4);
    float f[8] = {wa.x, wa.y, wa.z, wa.w, wb.x, wb.y, wb.z, wb.w};
#pragma unroll
    for (int i = 0; i < 4; ++i) {
        float f0 = valid ? f[2 * i] : 0.f;
        float f1 = valid ? f[2 * i + 1] : 0.f;
        unsigned h0 = bf16_rne(f0), h1 = bf16_rne(f1);
        float hf0 = __uint_as_float(h0 << 16), hf1 = __uint_as_float(h1 << 16);
        unsigned l0 = bf16_rne(f0 - hf0), l1 = bf16_rne(f1 - hf1);
        hh[i] = (h1 << 16) | h0;
        ll[i] = (l1 << 16) | l0;
    }
    wfh[gid] = *reinterpret_cast<uint4*>(hh);
    wfl[gid] = *reinterpret_cast<uint4*>(ll);
}

// ---------------- Kernel A: split-bf16 MFMA conv + fire + pool + argmin ----
// EXACT R8 conv body (single-ft weight residency: 64 weight regs AGPR-parked,
// VGPR~60, occupancy ~35% — the proven sweet spot; R9's ft-pair at 128 regs
// dropped occupancy to 19% and LOST 100 us). Added: R9's fused first-spike
// argmin epilogue (one atomicMin/block) so scan_kernel (~43 us) is deleted.
// res loop stays `#pragma unroll 1` (R7: full unroll -> 256 VGPR + spills).
template <bool PRE>
__global__ __launch_bounds__(256) void conv_pool_kernel(
    const float* __restrict__ x, const float* __restrict__ Wg,
    const uint4* __restrict__ wfh, const uint4* __restrict__ wfl,
    float* __restrict__ out, int* __restrict__ keys)
{
    __shared__ __align__(16) unsigned short xh[4][10][176];   // 13.75 KB
    __shared__ __align__(16) unsigned short xl[4][10][176];   // 13.75 KB
    __shared__ unsigned lmask[4][64];
    __shared__ int red[256];

    const int b       = blockIdx.x;
    const int coltile = b & 15;
    const int tt      = (b >> 4) % T_;
    const int sec     = b / 480;
    const int w0      = coltile * 128;     // pot-col base
    const int rowbase = 4 * sec;
    const int tid     = threadIdx.x;

    // ---- stage x: 10 rows x 176 cols -> hi/lo u16, 4 shifted copies ----
    for (int i = tid; i < 440; i += 256) {
        const int row = i / 44;
        const int c4  = i % 44;
        const int grow = (rowbase + row < H_) ? rowbase + row : H_ - 1;
        const int gc   = w0 + 4 * c4;
        float4 v;
        if (gc + 3 < WD_) {
            v = *reinterpret_cast<const float4*>(x + ((size_t)tt * H_ + grow) * WD_ + gc);
        } else {
            v.x = v.y = v.z = v.w = 0.f;
        }
        float f[4] = {v.x, v.y, v.z, v.w};
        unsigned short hq[4], lq[4];
#pragma unroll
        for (int e = 0; e < 4; ++e) {
            unsigned h = bf16_rne(f[e]);
            float hf = __uint_as_float(h << 16);
            unsigned l = bf16_rne(f[e] - hf);
            hq[e] = (unsigned short)h;
            lq[e] = (unsigned short)l;
        }
#pragma unroll
        for (int S = 0; S < 4; ++S)
#pragma unroll
            for (int e = 0; e < 4; ++e) {
                const int j = 4 * c4 + e - S;
                if (j >= 0 && j < 176) { xh[S][row][j] = hq[e]; xl[S][row][j] = lq[e]; }
            }
    }
    __syncthreads();

    const int L    = tid & 63;
    const int j_p  = tid >> 6;       // wave id = pot row
    const int q    = L >> 4;         // quad
    const int n16  = L & 15;         // A: m-index; B: fm-index

    // per-kk tap geometry (tau0 = 32kk + 8q -> weight row r, col c0)
    int preidx[8];
    int tau0s[8];
#pragma unroll
    for (int kk = 0; kk < 8; ++kk) {
        const int t0 = 32 * kk + 8 * q;
        const int r  = t0 / 40;
        const int c0 = t0 - 40 * r;
        tau0s[kk]  = t0;
        preidx[kk] = (j_p + r) * 176 + c0 + 8 * n16;
    }

    unsigned mask = 0;

#pragma unroll 1
    for (int ft = 0; ft < 4; ++ft) {
        const int fm = ft * 16 + n16;
        short8 wh[8], wl[8];
        if (PRE) {
            const int fb = (sec * 64 + ft * 16 + n16) * 32 + q;
#pragma unroll
            for (int kk = 0; kk < 8; ++kk) {
                uint4 hu = wfh[fb + 4 * kk];
                uint4 lu = wfl[fb + 4 * kk];
                union { uint4 u; short8 s; } c1, c2;
                c1.u = hu; c2.u = lu;
                wh[kk] = c1.s; wl[kk] = c2.s;
            }
        } else {
            // fallback: in-kernel build (used only if ws too small)
#pragma unroll
            for (int kk = 0; kk < 8; ++kk) {
                const int t0 = tau0s[kk];
                const bool wvalid = (t0 < 240) && (fm < FM);
                const float* wp = Wg + (size_t)sec * FM * 240 +
                                  (size_t)(wvalid ? fm : 0) * 240 + (wvalid ? t0 : 0);
                float4 wa = *reinterpret_cast<const float4*>(wp);
                float4 wb = *reinterpret_cast<const float4*>(wp + 4);
                float f[8] = {wa.x, wa.y, wa.z, wa.w, wb.x, wb.y, wb.z, wb.w};
                unsigned hh[4], ll[4];
#pragma unroll
                for (int i = 0; i < 4; ++i) {
                    float f0 = wvalid ? f[2 * i] : 0.f;
                    float f1 = wvalid ? f[2 * i + 1] : 0.f;
                    unsigned h0 = bf16_rne(f0), h1 = bf16_rne(f1);
                    float hf0 = __uint_as_float(h0 << 16), hf1 = __uint_as_float(h1 << 16);
                    unsigned l0 = bf16_rne(f0 - hf0), l1 = bf16_rne(f1 - hf1);
                    hh[i] = (h1 << 16) | h0;
                    ll[i] = (l1 << 16) | l0;
                }
                wh[kk] = *reinterpret_cast<short8*>(hh);
                wl[kk] = *reinterpret_cast<short8*>(ll);
            }
        }

#pragma unroll 1
        for (int res = 0; res < 8; ++res) {
            const int S   = res & 3;
            const int off = (res >> 2) << 2;          // 0 or 4 cols
            const unsigned short* hb = &xh[S][0][0] + off;
            const unsigned short* lb = &xl[S][0][0] + off;

            f32x4 acc = {0.f, 0.f, 0.f, 0.f};
#pragma unroll
            for (int kk = 0; kk < 8; ++kk) {
                short8 ah, al;
                if (off == 0) {                       // 16B-aligned: b128
                    ah = *reinterpret_cast<const short8*>(hb + preidx[kk]);
                    al = *reinterpret_cast<const short8*>(lb + preidx[kk]);
                } else {                              // 8B-aligned: 2x b64
                    short4v h0 = *reinterpret_cast<const short4v*>(hb + preidx[kk]);
                    short4v h1 = *reinterpret_cast<const short4v*>(hb + preidx[kk] + 4);
                    short4v l0 = *reinterpret_cast<const short4v*>(lb + preidx[kk]);
                    short4v l1 = *reinterpret_cast<const short4v*>(lb + preidx[kk] + 4);
                    ah = __builtin_shufflevector(h0, h1, 0, 1, 2, 3, 4, 5, 6, 7);
                    al = __builtin_shufflevector(l0, l1, 0, 1, 2, 3, 4, 5, 6, 7);
                }
                acc = __builtin_amdgcn_mfma_f32_16x16x32_bf16(ah, wh[kk], acc, 0, 0, 0);
                acc = __builtin_amdgcn_mfma_f32_16x16x32_bf16(al, wh[kk], acc, 0, 0, 0);
                acc = __builtin_amdgcn_mfma_f32_16x16x32_bf16(ah, wl[kk], acc, 0, 0, 0);
            }

            // ---- epilogue: repair borderline, set pool bits ----
#pragma unroll
            for (int reg = 0; reg < 4; ++reg) {
                float v = acc[reg];
                const int m   = q * 4 + reg;
                const int pcg = w0 + res + 8 * m;     // global pot col
                const bool valid = (fm < FM) && (pcg <= 2007);
                if (valid && __builtin_fabsf(v - THRESH) < MARGIN) {
                    float pot = 0.f;
#pragma unroll 1
                    for (int r2 = 0; r2 < 6; ++r2) {
                        const float* xr = x + ((size_t)tt * H_ + rowbase + j_p + r2) * WD_ + pcg;
                        const float* wr = Wg + (size_t)sec * FM * 240 + (size_t)fm * 240 + r2 * 40;
#pragma unroll 1
                        for (int c = 0; c < 40; ++c)
                            pot = fmaf(xr[c], wr[c], pot);
                    }
                    v = pot;
                }
                if (v > THRESH)
                    mask |= 1u << (reg * 8 + ft * 2 + (res >> 2));
            }
        }
    }

    lmask[j_p][L] = mask;
    __syncthreads();

    // ---- cross-wave OR + pooled write + fused first-spike argmin ----
    int mykey = 0x7fffffff;
    for (int e = tid; e < 2048; e += 256) {
        const int fmo = e >> 5, p = e & 31;
        const int m = p >> 1, rg = p & 1, ftc = fmo >> 4, fn = fmo & 15;
        const int lane = (m >> 2) * 16 + fn;
        const int bitpos = (m & 3) * 8 + ftc * 2 + rg;
        const unsigned bits = lmask[0][lane] | lmask[1][lane] |
                              lmask[2][lane] | lmask[3][lane];
        const int pg = coltile * 32 + p;
        const int spk = (bits >> bitpos) & 1u;
        if (fmo < FM && pg < WP) {
            out[((size_t)(sec * T_ + tt) * FM + fmo) * WP + pg] = spk ? 1.0f : 0.0f;
            if (spk) mykey = min(mykey, fmo * WP + pg);   // section-flat idx
        }
    }
    red[tid] = mykey;
    __syncthreads();
    for (int s = 128; s > 0; s >>= 1) {
        if (tid < s) red[tid] = min(red[tid], red[tid + s]);
        __syncthreads();
    }
    if (tid == 0 && red[0] != 0x7fffffff)
        atomicMin(&keys[sec], (tt << 15) | red[0]);
}

// ---------------- init (fallback only) ----------------
__global__ void init_kernel(int* __restrict__ ws)
{
    if (threadIdx.x < NSEC) ws[threadIdx.x] = 0x7fffffff;
}

// ---------------- Kernel D: finalize winners ----------------
__global__ void finalize_kernel(const int* __restrict__ ws, float* __restrict__ out)
{
    const int i = threadIdx.x;
    if (i < NSEC) {
        const int key = ws[i];
        float feat;
        if (key == 0x7fffffff) feat = -1.0f;
        else                   feat = (float)((key & 32767) / WP);
        out[POOLED_SIZE + i] = feat;
    }
}

extern "C" void kernel_launch(void* const* d_in, const int* in_sizes, int n_in,
                              void* d_out, int out_size, void* d_ws, size_t ws_size,
                              hipStream_t stream) {
    const float* x  = (const float*)d_in[0];
    const float* Wg = (const float*)d_in[1];
    float* out = (float*)d_out;
    int*   wsi = (int*)d_ws;
    uint4* wfh = (uint4*)((char*)d_ws + 256);
    uint4* wfl = wfh + NFRAG;

    const bool pre = ws_size >= 256 + (size_t)NFRAG * 16 * 2;   // 590 KB
    if (pre) {
        prep_kernel<<<dim3(72), dim3(256), 0, stream>>>(Wg, wsi, wfh, wfl);
        conv_pool_kernel<true><<<dim3(4320), dim3(256), 0, stream>>>(x, Wg, wfh, wfl, out, wsi);
    } else {
        init_kernel<<<dim3(1), dim3(64), 0, stream>>>(wsi);
        conv_pool_kernel<false><<<dim3(4320), dim3(256), 0, stream>>>(x, Wg, wfh, wfl, out, wsi);
    }
    finalize_kernel<<<dim3(1), dim3(16), 0, stream>>>(wsi, out);
}